// Round 1
// baseline (538.710 us; speedup 1.0000x reference)
//
#include <hip/hip_runtime.h>

// out[B,D] = sum_i k[i] * x[i][B,D]
// x: [6, 16384, 1024] fp32 (d_in[0]), k: [6] fp32 (d_in[1]), out: [16384,1024] fp32
// Memory-bound: 470 MB total traffic -> ~75 us floor at 6.3 TB/s.

#define PLANE_ELEMS (16384LL * 1024LL)   // elements per input plane
#define N_INPUTS 6

__global__ __launch_bounds__(256) void multidense_kernel(
    const float4* __restrict__ x,   // [6 * PLANE/4] as float4
    const float*  __restrict__ k,   // [6]
    float4* __restrict__ out,       // [PLANE/4]
    int n_vec) {
    int i = blockIdx.x * blockDim.x + threadIdx.x;
    if (i >= n_vec) return;

    const long long p = PLANE_ELEMS / 4;  // float4 stride between planes

    // Scalar kernels: same-address broadcast load, cached.
    float k0 = k[0], k1 = k[1], k2 = k[2], k3 = k[3], k4 = k[4], k5 = k[5];

    float4 a0 = x[i + 0 * p];
    float4 a1 = x[i + 1 * p];
    float4 a2 = x[i + 2 * p];
    float4 a3 = x[i + 3 * p];
    float4 a4 = x[i + 4 * p];
    float4 a5 = x[i + 5 * p];

    float4 r;
    r.x = k0 * a0.x + k1 * a1.x + k2 * a2.x + k3 * a3.x + k4 * a4.x + k5 * a5.x;
    r.y = k0 * a0.y + k1 * a1.y + k2 * a2.y + k3 * a3.y + k4 * a4.y + k5 * a5.y;
    r.z = k0 * a0.z + k1 * a1.z + k2 * a2.z + k3 * a3.z + k4 * a4.z + k5 * a5.z;
    r.w = k0 * a0.w + k1 * a1.w + k2 * a2.w + k3 * a3.w + k4 * a4.w + k5 * a5.w;

    out[i] = r;
}

extern "C" void kernel_launch(void* const* d_in, const int* in_sizes, int n_in,
                              void* d_out, int out_size, void* d_ws, size_t ws_size,
                              hipStream_t stream) {
    const float4* x = (const float4*)d_in[0];
    const float*  k = (const float*)d_in[1];
    float4* out = (float4*)d_out;

    const int n_vec = (int)(PLANE_ELEMS / 4);  // 4,194,304
    const int block = 256;
    const int grid  = (n_vec + block - 1) / block;  // 16384 blocks

    multidense_kernel<<<grid, block, 0, stream>>>(x, k, out, n_vec);
}

// Round 3
// 521.374 us; speedup vs baseline: 1.0332x; 1.0332x over previous
//
#include <hip/hip_runtime.h>

// out[B,D] = sum_i k[i] * x[i][B,D]
// x: [6, 16384, 1024] fp32 (d_in[0]), k: [6] fp32 (d_in[1]), out: [16384,1024] fp32
// Pure streaming, zero reuse: 402 MB read + 67 MB write -> ~75 us floor @ 6.3 TB/s.
// Grid-stride (2048 blocks x 256), unroll x2 -> 12 loads in flight/thread.
// Nontemporal hints: no byte is ever re-read, keep it out of L2/LLC.
// NOTE: __builtin_nontemporal_* rejects HIP_vector_type structs -> use clang
// native ext_vector_type(4) float.

typedef float vfloat4 __attribute__((ext_vector_type(4)));

#define PLANE_VEC (16384 * 1024 / 4)   // float4 per plane = 4,194,304
#define BLOCKS 2048
#define TPB 256

__global__ __launch_bounds__(TPB) void multidense_kernel(
    const vfloat4* __restrict__ x,   // [6 * PLANE_VEC]
    const float*   __restrict__ k,   // [6]
    vfloat4* __restrict__ out) {     // [PLANE_VEC]
    const int stride = BLOCKS * TPB;               // 524288
    int i = blockIdx.x * TPB + threadIdx.x;

    const float k0 = k[0], k1 = k[1], k2 = k[2], k3 = k[3], k4 = k[4], k5 = k[5];

    // PLANE_VEC / stride == 8 exactly; unroll 2 -> 4 outer iterations, no tail.
    #pragma unroll
    for (int it = 0; it < 4; ++it) {
        const int ia = i;
        const int ib = i + stride;

        vfloat4 a0 = __builtin_nontemporal_load(&x[ia + 0 * PLANE_VEC]);
        vfloat4 a1 = __builtin_nontemporal_load(&x[ia + 1 * PLANE_VEC]);
        vfloat4 a2 = __builtin_nontemporal_load(&x[ia + 2 * PLANE_VEC]);
        vfloat4 a3 = __builtin_nontemporal_load(&x[ia + 3 * PLANE_VEC]);
        vfloat4 a4 = __builtin_nontemporal_load(&x[ia + 4 * PLANE_VEC]);
        vfloat4 a5 = __builtin_nontemporal_load(&x[ia + 5 * PLANE_VEC]);
        vfloat4 b0 = __builtin_nontemporal_load(&x[ib + 0 * PLANE_VEC]);
        vfloat4 b1 = __builtin_nontemporal_load(&x[ib + 1 * PLANE_VEC]);
        vfloat4 b2 = __builtin_nontemporal_load(&x[ib + 2 * PLANE_VEC]);
        vfloat4 b3 = __builtin_nontemporal_load(&x[ib + 3 * PLANE_VEC]);
        vfloat4 b4 = __builtin_nontemporal_load(&x[ib + 4 * PLANE_VEC]);
        vfloat4 b5 = __builtin_nontemporal_load(&x[ib + 5 * PLANE_VEC]);

        vfloat4 ra = k0*a0 + k1*a1 + k2*a2 + k3*a3 + k4*a4 + k5*a5;
        vfloat4 rb = k0*b0 + k1*b1 + k2*b2 + k3*b3 + k4*b4 + k5*b5;

        __builtin_nontemporal_store(ra, &out[ia]);
        __builtin_nontemporal_store(rb, &out[ib]);

        i += 2 * stride;
    }
}

extern "C" void kernel_launch(void* const* d_in, const int* in_sizes, int n_in,
                              void* d_out, int out_size, void* d_ws, size_t ws_size,
                              hipStream_t stream) {
    const vfloat4* x = (const vfloat4*)d_in[0];
    const float*   k = (const float*)d_in[1];
    vfloat4* out = (vfloat4*)d_out;

    multidense_kernel<<<BLOCKS, TPB, 0, stream>>>(x, k, out);
}